// Round 1
// baseline (17801.573 us; speedup 1.0000x reference)
//
#include <hip/hip_runtime.h>

#define DIM 64

// ---------------- kernels ----------------

__global__ void count_deg(const int* __restrict__ row, const int* __restrict__ col,
                          float* __restrict__ deg_u, float* __restrict__ deg_i, int E) {
    int e = blockIdx.x * blockDim.x + threadIdx.x;
    if (e < E) {
        atomicAdd(&deg_u[row[e]], 1.0f);
        atomicAdd(&deg_i[col[e]], 1.0f);
    }
}

__global__ void rsqrt_clip(float* __restrict__ d, int n) {
    int i = blockIdx.x * blockDim.x + threadIdx.x;
    if (i < n) d[i] = rsqrtf(fmaxf(d[i], 1.0f));
}

__global__ void compute_norm(const int* __restrict__ row, const int* __restrict__ col,
                             const float* __restrict__ w,
                             const float* __restrict__ ru, const float* __restrict__ ri,
                             float* __restrict__ norm, int E, int has_w) {
    int e = blockIdx.x * blockDim.x + threadIdx.x;
    if (e < E) {
        float wv = has_w ? w[e] : 1.0f;
        norm[e] = ru[row[e]] * ri[col[e]] * wv;
    }
}

// cur = src; out = src   (init running sum and current embedding from input)
__global__ void init2(const float* __restrict__ src, float* __restrict__ cur,
                      float* __restrict__ out, int n4) {
    int i = blockIdx.x * blockDim.x + threadIdx.x;
    if (i < n4) {
        float4 v = ((const float4*)src)[i];
        ((float4*)cur)[i] = v;
        ((float4*)out)[i] = v;
    }
}

// dst = src (float4)
__global__ void copy4(const float* __restrict__ src, float* __restrict__ dst, int n4) {
    int i = blockIdx.x * blockDim.x + threadIdx.x;
    if (i < n4) ((float4*)dst)[i] = ((const float4*)src)[i];
}

// out = (out + add) * scale   (float4)
__global__ void addscale(float* __restrict__ out, const float* __restrict__ add,
                         int n4, float scale) {
    int i = blockIdx.x * blockDim.x + threadIdx.x;
    if (i < n4) {
        float4 o = ((float4*)out)[i];
        float4 a = ((const float4*)add)[i];
        o.x = (o.x + a.x) * scale;
        o.y = (o.y + a.y) * scale;
        o.z = (o.z + a.z) * scale;
        o.w = (o.w + a.w) * scale;
        ((float4*)out)[i] = o;
    }
}

// 16 threads per edge; thread q handles float4 #q of the 64-dim row.
// u_new[row] += i_old[col]*n ; i_new[col] += u_old[row]*n  (atomics)
__global__ void edge_prop(const int* __restrict__ row, const int* __restrict__ col,
                          const float* __restrict__ norm,
                          const float* __restrict__ u_old, const float* __restrict__ i_old,
                          float* __restrict__ u_new, float* __restrict__ i_new, int E) {
    int t = blockIdx.x * blockDim.x + threadIdx.x;
    int e = t >> 4;
    if (e >= E) return;
    int q = (t & 15) * 4;
    int r = row[e];
    int c = col[e];
    float n = norm[e];
    float4 iv = *(const float4*)(i_old + (size_t)c * DIM + q);
    float4 uv = *(const float4*)(u_old + (size_t)r * DIM + q);
    float* up = u_new + (size_t)r * DIM + q;
    float* ip = i_new + (size_t)c * DIM + q;
    atomicAdd(up + 0, iv.x * n);
    atomicAdd(up + 1, iv.y * n);
    atomicAdd(up + 2, iv.z * n);
    atomicAdd(up + 3, iv.w * n);
    atomicAdd(ip + 0, uv.x * n);
    atomicAdd(ip + 1, uv.y * n);
    atomicAdd(ip + 2, uv.z * n);
    atomicAdd(ip + 3, uv.w * n);
}

// ---------------- host ----------------

static inline int cdiv(long long a, int b) { return (int)((a + b - 1) / b); }

extern "C" void kernel_launch(void* const* d_in, const int* in_sizes, int n_in,
                              void* d_out, int out_size, void* d_ws, size_t ws_size,
                              hipStream_t stream) {
    const int*   ei  = (const int*)d_in[0];      // (2, E_POS): row, then col
    const int*   nei = (const int*)d_in[1];      // (2, E_NEG)
    const float* ew  = (const float*)d_in[2];    // (E_POS,)
    const float* uep = (const float*)d_in[3];    // (NU, 64)
    const float* iep = (const float*)d_in[4];    // (NI, 64)
    const float* uen = (const float*)d_in[5];
    const float* ien = (const float*)d_in[6];
    float* out = (float*)d_out;

    const int E_POS = in_sizes[2];
    const int E_NEG = in_sizes[1] / 2;
    const int NU = in_sizes[3] / DIM;
    const int NI = in_sizes[4] / DIM;
    const int NTOT = (NU + NI) * DIM;            // one graph's emb block, floats
    const int N4 = NTOT / 4;

    // workspace layout (floats)
    float* ws = (float*)d_ws;
    size_t off = 0;
    float* buf0 = ws + off; off += (size_t)NTOT;     // ping
    float* buf1 = ws + off; off += (size_t)NTOT;     // pong
    float* norm = ws + off; off += (size_t)E_POS;    // reused for neg (E_NEG < E_POS)
    float* ru   = ws + off; off += (size_t)NU;       // deg_u -> rsqrt
    float* ri   = ws + off; off += (size_t)NI;       // deg_i -> rsqrt (contiguous after ru)

    const int B = 256;

    for (int g = 0; g < 2; ++g) {
        const int   E    = g == 0 ? E_POS : E_NEG;
        const int*  row  = g == 0 ? ei : nei;
        const int*  col  = row + E;
        const float* wv  = g == 0 ? ew : nullptr;
        const float* ue0 = g == 0 ? uep : uen;
        const float* ie0 = g == 0 ? iep : ien;
        float* outg = out + (size_t)g * NTOT;

        // degree -> rsqrt -> per-edge norm (loop-invariant, computed once)
        hipMemsetAsync(ru, 0, (size_t)(NU + NI) * sizeof(float), stream);
        count_deg<<<cdiv(E, B), B, 0, stream>>>(row, col, ru, ri, E);
        rsqrt_clip<<<cdiv(NU + NI, B), B, 0, stream>>>(ru, NU + NI);
        compute_norm<<<cdiv(E, B), B, 0, stream>>>(row, col, wv, ru, ri, norm, E,
                                                   g == 0 ? 1 : 0);

        // sum = emb0; cur = emb0
        init2<<<cdiv(NU * DIM / 4, B), B, 0, stream>>>(ue0, buf0, outg, NU * DIM / 4);
        init2<<<cdiv(NI * DIM / 4, B), B, 0, stream>>>(ie0, buf0 + (size_t)NU * DIM,
                                                       outg + (size_t)NU * DIM, NI * DIM / 4);

        float* cur = buf0;
        float* nxt = buf1;
        for (int l = 0; l < 4; ++l) {
            // nxt = cur, then atomically add propagated neighbors
            copy4<<<cdiv(N4, B), B, 0, stream>>>(cur, nxt, N4);
            edge_prop<<<cdiv((long long)E * 16, B), B, 0, stream>>>(
                row, col, norm, cur, cur + (size_t)NU * DIM,
                nxt, nxt + (size_t)NU * DIM, E);
            // sum += nxt ; on last layer fold in the 1/(L+1) scale
            float scale = (l == 3) ? 0.2f : 1.0f;
            addscale<<<cdiv(N4, B), B, 0, stream>>>(outg, nxt, N4, scale);
            float* t = cur; cur = nxt; nxt = t;
        }
    }
}

// Round 2
// 1870.178 us; speedup vs baseline: 9.5187x; 9.5187x over previous
//
#include <hip/hip_runtime.h>

#define DIM 64
#define CHUNK 2048   // scan chunk: 256 threads x 8 elements

// ---------------- CSR build kernels ----------------

__global__ void hist_kernel(const int* __restrict__ row, const int* __restrict__ col,
                            int* __restrict__ deg_u, int* __restrict__ deg_i, int E) {
    int e = blockIdx.x * blockDim.x + threadIdx.x;
    if (e < E) {
        atomicAdd(&deg_u[row[e]], 1);
        atomicAdd(&deg_i[col[e]], 1);
    }
}

__global__ void fill_rsqrt(const int* __restrict__ deg, float* __restrict__ r, int n) {
    int i = blockIdx.x * blockDim.x + threadIdx.x;
    if (i < n) r[i] = rsqrtf(fmaxf((float)deg[i], 1.0f));
}

__global__ void partial_sums(const int* __restrict__ deg, int* __restrict__ bsum, int n) {
    __shared__ int s[256];
    int t = threadIdx.x;
    int base = blockIdx.x * CHUNK + t * 8;
    int loc = 0;
    for (int k = 0; k < 8; k++) { int j = base + k; if (j < n) loc += deg[j]; }
    s[t] = loc; __syncthreads();
    for (int ofs = 128; ofs > 0; ofs >>= 1) { if (t < ofs) s[t] += s[t + ofs]; __syncthreads(); }
    if (t == 0) bsum[blockIdx.x] = s[0];
}

__global__ void scan_small(int* __restrict__ bsum, int nb) {
    if (threadIdx.x == 0 && blockIdx.x == 0) {
        int acc = 0;
        for (int i = 0; i < nb; i++) { int x = bsum[i]; bsum[i] = acc; acc += x; }
    }
}

// exclusive scan of deg -> offs and cur (deg may alias cur)
__global__ void scan_chunk(const int* __restrict__ deg, int* __restrict__ offs,
                           int* __restrict__ cur, const int* __restrict__ bsum, int n) {
    __shared__ int s[256];
    int t = threadIdx.x;
    int base = blockIdx.x * CHUNK + t * 8;
    int v[8]; int loc = 0;
    for (int k = 0; k < 8; k++) { int j = base + k; v[k] = (j < n) ? deg[j] : 0; loc += v[k]; }
    s[t] = loc; __syncthreads();
    // Hillis-Steele inclusive scan over 256 thread sums
    for (int ofs = 1; ofs < 256; ofs <<= 1) {
        int x = (t >= ofs) ? s[t - ofs] : 0;
        __syncthreads();
        s[t] += x;
        __syncthreads();
    }
    int excl = (t == 0) ? 0 : s[t - 1];
    int run = bsum[blockIdx.x] + excl;
    for (int k = 0; k < 8; k++) {
        int j = base + k;
        if (j < n) { offs[j] = run; cur[j] = run; }
        run += v[k];
    }
}

__global__ void scatter_kernel(const int* __restrict__ row, const int* __restrict__ col,
                               const float* __restrict__ w, int has_w,
                               const float* __restrict__ ru, const float* __restrict__ ri,
                               int* __restrict__ cur_u, int* __restrict__ cur_i,
                               int2* __restrict__ adj_u, int2* __restrict__ adj_i, int E) {
    int e = blockIdx.x * blockDim.x + threadIdx.x;
    if (e >= E) return;
    int r = row[e], c = col[e];
    float wv = has_w ? w[e] : 1.0f;
    float nrm = ru[r] * ri[c] * wv;
    int nb = __float_as_int(nrm);
    int pu = atomicAdd(&cur_u[r], 1);
    adj_u[pu] = make_int2(c, nb);
    int pi = atomicAdd(&cur_i[c], 1);
    adj_i[pi] = make_int2(r, nb);
}

// ---------------- embedding kernels ----------------

// cur = src; sum = src
__global__ void init2(const float* __restrict__ src, float* __restrict__ cur,
                      float* __restrict__ sum, int n4) {
    int i = blockIdx.x * blockDim.x + threadIdx.x;
    if (i < n4) {
        float4 v = ((const float4*)src)[i];
        ((float4*)cur)[i] = v;
        ((float4*)sum)[i] = v;
    }
}

// Gather aggregation: 16 lanes per vertex, lane q owns float4 #q of the row.
// self_new[v] = self_old[v] + sum_{e in CSR[v]} nrm_e * src[nbr_e]
// sum[v] = (sum[v] + self_new[v]) * scale
// self_new may alias self_old (only own row is read from the self table).
__global__ void aggregate(const int* __restrict__ offs, const int* __restrict__ endo,
                          const int2* __restrict__ adj,
                          const float* __restrict__ src,
                          const float* __restrict__ self_old,
                          float* __restrict__ self_new,
                          float* __restrict__ sum,
                          float scale, int N) {
    int t = blockIdx.x * blockDim.x + threadIdx.x;
    int v = t >> 4;
    if (v >= N) return;
    int q = (t & 15) * 4;
    size_t rowoff = (size_t)v * DIM + q;
    float4 acc = *(const float4*)(self_old + rowoff);
    int s = offs[v], e = endo[v];
    int i = s;
    for (; i + 1 < e; i += 2) {
        int2 m0 = adj[i];
        int2 m1 = adj[i + 1];
        float n0 = __int_as_float(m0.y);
        float n1 = __int_as_float(m1.y);
        float4 b0 = *(const float4*)(src + (size_t)m0.x * DIM + q);
        float4 b1 = *(const float4*)(src + (size_t)m1.x * DIM + q);
        acc.x += b0.x * n0 + b1.x * n1;
        acc.y += b0.y * n0 + b1.y * n1;
        acc.z += b0.z * n0 + b1.z * n1;
        acc.w += b0.w * n0 + b1.w * n1;
    }
    if (i < e) {
        int2 m0 = adj[i];
        float n0 = __int_as_float(m0.y);
        float4 b0 = *(const float4*)(src + (size_t)m0.x * DIM + q);
        acc.x += b0.x * n0;
        acc.y += b0.y * n0;
        acc.z += b0.z * n0;
        acc.w += b0.w * n0;
    }
    *(float4*)(self_new + rowoff) = acc;
    float4 sm = *(const float4*)(sum + rowoff);
    sm.x = (sm.x + acc.x) * scale;
    sm.y = (sm.y + acc.y) * scale;
    sm.z = (sm.z + acc.z) * scale;
    sm.w = (sm.w + acc.w) * scale;
    *(float4*)(sum + rowoff) = sm;
}

// ---------------- host ----------------

static inline int cdiv(long long a, int b) { return (int)((a + b - 1) / b); }

extern "C" void kernel_launch(void* const* d_in, const int* in_sizes, int n_in,
                              void* d_out, int out_size, void* d_ws, size_t ws_size,
                              hipStream_t stream) {
    const int*   ei  = (const int*)d_in[0];      // (2, E_POS)
    const int*   nei = (const int*)d_in[1];      // (2, E_NEG)
    const float* ew  = (const float*)d_in[2];    // (E_POS,)
    const float* uep = (const float*)d_in[3];
    const float* iep = (const float*)d_in[4];
    const float* uen = (const float*)d_in[5];
    const float* ien = (const float*)d_in[6];
    float* out = (float*)d_out;

    const int E_POS = in_sizes[2];
    const int E_NEG = in_sizes[1] / 2;
    const int NU = in_sizes[3] / DIM;
    const int NI = in_sizes[4] / DIM;
    const int NTOT = (NU + NI) * DIM;

    // ---- workspace layout (4-byte units) ----
    char* ws = (char*)d_ws;
    size_t off = 0;
    auto alloc = [&](size_t elems4) { void* p = ws + off; off += elems4 * 4; return p; };
    float* u_emb  = (float*)alloc((size_t)NU * DIM);   // user table (in-place updated)
    float* i_emb0 = (float*)alloc((size_t)NI * DIM);   // item ping
    float* i_emb1 = (float*)alloc((size_t)NI * DIM);   // item pong
    int*   offs_u = (int*)alloc(NU);
    int*   offs_i = (int*)alloc(NI);
    int*   cur_u  = (int*)alloc(NU);                   // deg -> cursor -> end
    int*   cur_i  = (int*)alloc(NI);                   // contiguous after cur_u
    float* ru     = (float*)alloc(NU);
    float* ri     = (float*)alloc(NI);
    int*   bsum   = (int*)alloc(256);
    int2*  adj_u  = (int2*)alloc((size_t)E_POS * 2);
    int2*  adj_i  = (int2*)alloc((size_t)E_POS * 2);

    const int B = 256;
    const int nb_u = cdiv(NU, CHUNK);
    const int nb_i = cdiv(NI, CHUNK);

    for (int g = 0; g < 2; ++g) {
        const int    E   = g == 0 ? E_POS : E_NEG;
        const int*   row = g == 0 ? ei : nei;
        const int*   col = row + E;
        const float* wv  = g == 0 ? ew : nullptr;
        const float* ue0 = g == 0 ? uep : uen;
        const float* ie0 = g == 0 ? iep : ien;
        float* sum_u = out + (size_t)g * NTOT;
        float* sum_i = sum_u + (size_t)NU * DIM;

        // ---- CSR build (once per graph, reused across 4 layers) ----
        hipMemsetAsync(cur_u, 0, (size_t)(NU + NI) * sizeof(int), stream);
        hist_kernel<<<cdiv(E, B), B, 0, stream>>>(row, col, cur_u, cur_i, E);
        fill_rsqrt<<<cdiv(NU, B), B, 0, stream>>>(cur_u, ru, NU);
        fill_rsqrt<<<cdiv(NI, B), B, 0, stream>>>(cur_i, ri, NI);
        // exclusive scans (deg lives in cur_*, overwritten with cursors)
        partial_sums<<<nb_u, B, 0, stream>>>(cur_u, bsum, NU);
        scan_small<<<1, 64, 0, stream>>>(bsum, nb_u);
        scan_chunk<<<nb_u, B, 0, stream>>>(cur_u, offs_u, cur_u, bsum, NU);
        partial_sums<<<nb_i, B, 0, stream>>>(cur_i, bsum, NI);
        scan_small<<<1, 64, 0, stream>>>(bsum, nb_i);
        scan_chunk<<<nb_i, B, 0, stream>>>(cur_i, offs_i, cur_i, bsum, NI);
        scatter_kernel<<<cdiv(E, B), B, 0, stream>>>(row, col, wv, g == 0 ? 1 : 0,
                                                     ru, ri, cur_u, cur_i,
                                                     adj_u, adj_i, E);
        // after scatter: cur_u[v] == offs_u[v] + deg_u[v]  (end offsets)

        // ---- init embeddings + running sums ----
        init2<<<cdiv(NU * DIM / 4, B), B, 0, stream>>>(ue0, u_emb, sum_u, NU * DIM / 4);
        init2<<<cdiv(NI * DIM / 4, B), B, 0, stream>>>(ie0, i_emb0, sum_i, NI * DIM / 4);

        float* icur = i_emb0;
        float* inew = i_emb1;
        for (int l = 0; l < 4; ++l) {
            float scale = (l == 3) ? 0.2f : 1.0f;
            // items: out-of-place (reads old user table)
            aggregate<<<cdiv((long long)NI * 16, B), B, 0, stream>>>(
                offs_i, cur_i, adj_i, u_emb, icur, inew, sum_i, scale, NI);
            // users: in-place (reads old item table icur; only own user row)
            aggregate<<<cdiv((long long)NU * 16, B), B, 0, stream>>>(
                offs_u, cur_u, adj_u, icur, u_emb, u_emb, sum_u, scale, NU);
            float* t = icur; icur = inew; inew = t;
        }
    }
}

// Round 3
// 1840.921 us; speedup vs baseline: 9.6699x; 1.0159x over previous
//
#include <hip/hip_runtime.h>

#define DIM 64
#define CHUNK 2048   // scan chunk: 256 threads x 8 elements

// ---------------- CSR build kernels (combined user+item vertex space) ----------------
// Vertex space: users [0, NU), items [NU, NU+NI). deg/offs/cur/rs all length NU+NI.
// adj is ONE array of 2E entries: user segments first (positions [0,E)), item segments
// ([E,2E)) — guaranteed by the combined exclusive scan. Neighbor ids stored LOCAL
// (item id for user rows, user id for item rows).

__global__ void hist_kernel(const int* __restrict__ row, const int* __restrict__ col,
                            int* __restrict__ deg, int NU, int E) {
    int e = blockIdx.x * blockDim.x + threadIdx.x;
    if (e < E) {
        atomicAdd(&deg[row[e]], 1);
        atomicAdd(&deg[NU + col[e]], 1);
    }
}

__global__ void fill_rsqrt(const int* __restrict__ deg, float* __restrict__ r, int n) {
    int i = blockIdx.x * blockDim.x + threadIdx.x;
    if (i < n) r[i] = rsqrtf(fmaxf((float)deg[i], 1.0f));
}

__global__ void partial_sums(const int* __restrict__ deg, int* __restrict__ bsum, int n) {
    __shared__ int s[256];
    int t = threadIdx.x;
    int base = blockIdx.x * CHUNK + t * 8;
    int loc = 0;
    for (int k = 0; k < 8; k++) { int j = base + k; if (j < n) loc += deg[j]; }
    s[t] = loc; __syncthreads();
    for (int ofs = 128; ofs > 0; ofs >>= 1) { if (t < ofs) s[t] += s[t + ofs]; __syncthreads(); }
    if (t == 0) bsum[blockIdx.x] = s[0];
}

// parallel exclusive scan of bsum[0..nb), nb <= 256
__global__ void scan_block(int* __restrict__ bsum, int nb) {
    __shared__ int s[256];
    int t = threadIdx.x;
    int x = (t < nb) ? bsum[t] : 0;
    s[t] = x; __syncthreads();
    for (int ofs = 1; ofs < 256; ofs <<= 1) {
        int y = (t >= ofs) ? s[t - ofs] : 0;
        __syncthreads();
        s[t] += y;
        __syncthreads();
    }
    if (t < nb) bsum[t] = s[t] - x;   // inclusive - self = exclusive
}

// exclusive scan of deg -> offs and cur (deg may alias cur)
__global__ void scan_chunk(const int* __restrict__ deg, int* __restrict__ offs,
                           int* __restrict__ cur, const int* __restrict__ bsum, int n) {
    __shared__ int s[256];
    int t = threadIdx.x;
    int base = blockIdx.x * CHUNK + t * 8;
    int v[8]; int loc = 0;
    for (int k = 0; k < 8; k++) { int j = base + k; v[k] = (j < n) ? deg[j] : 0; loc += v[k]; }
    s[t] = loc; __syncthreads();
    for (int ofs = 1; ofs < 256; ofs <<= 1) {
        int x = (t >= ofs) ? s[t - ofs] : 0;
        __syncthreads();
        s[t] += x;
        __syncthreads();
    }
    int excl = (t == 0) ? 0 : s[t - 1];
    int run = bsum[blockIdx.x] + excl;
    for (int k = 0; k < 8; k++) {
        int j = base + k;
        if (j < n) { offs[j] = run; cur[j] = run; }
        run += v[k];
    }
}

__global__ void scatter_kernel(const int* __restrict__ row, const int* __restrict__ col,
                               const float* __restrict__ w, int has_w,
                               const float* __restrict__ rs,
                               int* __restrict__ cur, int2* __restrict__ adj,
                               int NU, int E) {
    int e = blockIdx.x * blockDim.x + threadIdx.x;
    if (e >= E) return;
    int r = row[e], c = col[e];
    float wv = has_w ? w[e] : 1.0f;
    float nrm = rs[r] * rs[NU + c] * wv;
    int nb = __float_as_int(nrm);
    int pu = atomicAdd(&cur[r], 1);
    adj[pu] = make_int2(c, nb);          // user row -> local item id
    int pi = atomicAdd(&cur[NU + c], 1);
    adj[pi] = make_int2(r, nb);          // item row -> user id
}

// ---------------- embedding kernels ----------------

// cur = src; sum = src
__global__ void init2(const float* __restrict__ src, float* __restrict__ cur,
                      float* __restrict__ sum, int n4) {
    int i = blockIdx.x * blockDim.x + threadIdx.x;
    if (i < n4) {
        float4 v = ((const float4*)src)[i];
        ((float4*)cur)[i] = v;
        ((float4*)sum)[i] = v;
    }
}

// One wave per vertex; lane l owns element l of the 64-float row.
// CSR metadata reads forced wave-uniform (readfirstlane) -> scalar loads.
// self_new[v] = self_old[v] + sum_e nrm_e * src[nbr_e]; sum = (sum + self_new)*scale.
// self_new may alias self_old (only own row read from self table).
__global__ void aggregate(const int* __restrict__ offs, const int* __restrict__ endo,
                          const int2* __restrict__ adj,
                          const float* __restrict__ src,
                          const float* __restrict__ self_old,
                          float* __restrict__ self_new,
                          float* __restrict__ sum,
                          float scale, int N) {
    int v = blockIdx.x * (blockDim.x >> 6) + (threadIdx.x >> 6);
    if (v >= N) return;
    v = __builtin_amdgcn_readfirstlane(v);     // provably wave-uniform -> s_loads
    int l = threadIdx.x & 63;
    size_t rowoff = (size_t)v * DIM + l;
    float acc = self_old[rowoff];
    int s = offs[v], e = endo[v];
    int i = s;
    for (; i + 3 < e; i += 4) {
        int2 m0 = adj[i];
        int2 m1 = adj[i + 1];
        int2 m2 = adj[i + 2];
        int2 m3 = adj[i + 3];
        float b0 = src[(size_t)m0.x * DIM + l];
        float b1 = src[(size_t)m1.x * DIM + l];
        float b2 = src[(size_t)m2.x * DIM + l];
        float b3 = src[(size_t)m3.x * DIM + l];
        acc += b0 * __int_as_float(m0.y);
        acc += b1 * __int_as_float(m1.y);
        acc += b2 * __int_as_float(m2.y);
        acc += b3 * __int_as_float(m3.y);
    }
    for (; i < e; i++) {
        int2 m = adj[i];
        acc += src[(size_t)m.x * DIM + l] * __int_as_float(m.y);
    }
    self_new[rowoff] = acc;
    float sm = sum[rowoff];
    sum[rowoff] = (sm + acc) * scale;
}

// ---------------- host ----------------

static inline int cdiv(long long a, int b) { return (int)((a + b - 1) / b); }

extern "C" void kernel_launch(void* const* d_in, const int* in_sizes, int n_in,
                              void* d_out, int out_size, void* d_ws, size_t ws_size,
                              hipStream_t stream) {
    const int*   ei  = (const int*)d_in[0];      // (2, E_POS)
    const int*   nei = (const int*)d_in[1];      // (2, E_NEG)
    const float* ew  = (const float*)d_in[2];    // (E_POS,)
    const float* uep = (const float*)d_in[3];
    const float* iep = (const float*)d_in[4];
    const float* uen = (const float*)d_in[5];
    const float* ien = (const float*)d_in[6];
    float* out = (float*)d_out;

    const int E_POS = in_sizes[2];
    const int E_NEG = in_sizes[1] / 2;
    const int NU = in_sizes[3] / DIM;
    const int NI = in_sizes[4] / DIM;
    const int NV = NU + NI;
    const int NTOT = NV * DIM;

    // ---- workspace layout (4-byte units) ----
    char* ws = (char*)d_ws;
    size_t off = 0;
    auto alloc = [&](size_t elems4) { void* p = ws + off; off += elems4 * 4; return p; };
    float* u_emb = (float*)alloc((size_t)NU * DIM);   // user table (in-place updated)
    float* i_emb0 = (float*)alloc((size_t)NI * DIM);  // item ping
    float* i_emb1 = (float*)alloc((size_t)NI * DIM);  // item pong
    int*   offs = (int*)alloc(NV);
    int*   cur  = (int*)alloc(NV);                    // deg -> cursor -> end
    float* rs   = (float*)alloc(NV);
    int*   bsum = (int*)alloc(256);
    int2*  adj  = (int2*)alloc((size_t)E_POS * 4);    // 2E entries x int2

    const int B = 256;
    const int nb = cdiv(NV, CHUNK);                   // <= 256 required by scan_block

    for (int g = 0; g < 2; ++g) {
        const int    E   = g == 0 ? E_POS : E_NEG;
        const int*   row = g == 0 ? ei : nei;
        const int*   col = row + E;
        const float* wv  = g == 0 ? ew : nullptr;
        const float* ue0 = g == 0 ? uep : uen;
        const float* ie0 = g == 0 ? iep : ien;
        float* sum_u = out + (size_t)g * NTOT;
        float* sum_i = sum_u + (size_t)NU * DIM;

        // ---- CSR build (combined vertex space, once per graph) ----
        hipMemsetAsync(cur, 0, (size_t)NV * sizeof(int), stream);
        hist_kernel<<<cdiv(E, B), B, 0, stream>>>(row, col, cur, NU, E);
        fill_rsqrt<<<cdiv(NV, B), B, 0, stream>>>(cur, rs, NV);
        partial_sums<<<nb, B, 0, stream>>>(cur, bsum, NV);
        scan_block<<<1, 256, 0, stream>>>(bsum, nb);
        scan_chunk<<<nb, B, 0, stream>>>(cur, offs, cur, bsum, NV);
        scatter_kernel<<<cdiv(E, B), B, 0, stream>>>(row, col, wv, g == 0 ? 1 : 0,
                                                     rs, cur, adj, NU, E);
        // after scatter: cur[v] == offs[v] + deg[v] (end offsets)

        // ---- init embeddings + running sums ----
        init2<<<cdiv(NU * DIM / 4, B), B, 0, stream>>>(ue0, u_emb, sum_u, NU * DIM / 4);
        init2<<<cdiv(NI * DIM / 4, B), B, 0, stream>>>(ie0, i_emb0, sum_i, NI * DIM / 4);

        float* icur = i_emb0;
        float* inew = i_emb1;
        for (int l = 0; l < 4; ++l) {
            float scale = (l == 3) ? 0.2f : 1.0f;
            // items first: out-of-place, reads OLD user table
            aggregate<<<cdiv(NI, 4), B, 0, stream>>>(
                offs + NU, cur + NU, adj, u_emb, icur, inew, sum_i, scale, NI);
            // users: in-place, reads OLD item table icur
            aggregate<<<cdiv(NU, 4), B, 0, stream>>>(
                offs, cur, adj, icur, u_emb, u_emb, sum_u, scale, NU);
            float* t = icur; icur = inew; inew = t;
        }
    }
}